// Round 13
// baseline (221.435 us; speedup 1.0000x reference)
//
#include <hip/hip_runtime.h>

constexpr int NNODES = 50000;
constexpr int NEDGES = 800000;
constexpr int CAP = 64;   // bucket capacity; deg ~ Poisson(16), P(deg>=64) ~ 1e-19

constexpr int NPART = 8;
constexpr int PSIZE = NNODES / NPART;   // 6250
constexpr int FCH = 2048;               // edges scanned per fill block (8/thread)
constexpr int QCAP = 640;               // matches/block: mean 256, sd ~15 (25 sigma)

constexpr int CHUNKS = (NEDGES + FCH - 1) / FCH;   // 391
constexpr int TILE_ITEMS = (NNODES + 63) / 64;     // 782 == CHUNKS*2 (10-way interleave)
constexpr int PACK_TOT = 43008;

typedef __attribute__((ext_vector_type(8))) short short8;    // 8 bf16 (4 VGPRs)
typedef __attribute__((ext_vector_type(8))) unsigned short ushort8;
typedef __attribute__((ext_vector_type(4))) float f32x4;

__device__ __forceinline__ unsigned short f2b(float f) {   // fp32 -> bf16 RTN-even
    unsigned int u = __float_as_uint(f);
    u += 0x7FFFu + ((u >> 16) & 1u);
    return (unsigned short)(u >> 16);
}
__device__ __forceinline__ float b2f(unsigned short u) {   // exact
    return __uint_as_float(((unsigned int)u) << 16);
}
// packed edge record: low16 = src node id, high16 = bf16 bits of val
__device__ __forceinline__ float recval(unsigned int rec) {
    return __uint_as_float(rec & 0xFFFF0000u);
}

// ---------------------------------------------------------------------------
// Pack W[K][N] (fp32) -> MFMA B-fragment order (bf16).
// ---------------------------------------------------------------------------
template <int N, int K>
__device__ __forceinline__ void pack_one(int idx, const float* __restrict__ W,
                                         unsigned short* __restrict__ Wp) {
    constexpr int KS = K / 32;
    int j = idx & 7;
    int lane = (idx >> 3) & 63;
    int t = idx >> 9;
    int nt = t / KS, ks = t % KS;
    int n = nt * 16 + (lane & 15);
    int k = ks * 32 + (lane >> 4) * 8 + j;
    Wp[idx] = f2b(W[(size_t)k * N + n]);
}

__global__ __launch_bounds__(256) void prep_kernel(
        const float* __restrict__ W1, const float* __restrict__ W2,
        const float* __restrict__ W3, const float* __restrict__ W4,
        unsigned short* __restrict__ Wp1, unsigned short* __restrict__ Wp2,
        unsigned short* __restrict__ Wp3, unsigned short* __restrict__ Wp4) {
    int p = blockIdx.x * 256 + threadIdx.x;
    if (p < 16384) pack_one<128, 128>(p, W1, Wp1);
    else if (p < 32768) pack_one<128, 128>(p - 16384, W2, Wp2);
    else if (p < 40960) pack_one<64, 128>(p - 32768, W3, Wp3);
    else if (p < 43008) pack_one<32, 64>(p - 40960, W4, Wp4);
}

// ---------------------------------------------------------------------------
// MFMA bf16 GEMM tile (64 rows x full N). Fragment maps per learn_hip m89/m120.
// ---------------------------------------------------------------------------
template <int N, int K, bool AF32>
__device__ __forceinline__ void gemm_item(int t, const void* __restrict__ Hv,
                                          const unsigned short* __restrict__ Wp,
                                          unsigned short* __restrict__ Sb) {
    constexpr int NT = N / 16, KS = K / 32;
    const int lane = threadIdx.x & 63;
    const int wave = threadIdx.x >> 6;
    const int waveRow = t * 64 + wave * 16;
    const int m = lane & 15, quad = lane >> 4;
    int arow = waveRow + m;
    if (arow >= NNODES) arow = NNODES - 1;      // clamp; stores are guarded

    f32x4 acc[NT];
#pragma unroll
    for (int nt = 0; nt < NT; ++nt) acc[nt] = (f32x4){0.f, 0.f, 0.f, 0.f};

#pragma unroll
    for (int ks = 0; ks < KS; ++ks) {
        short8 a;
        if (AF32) {
            const float* hp = (const float*)Hv + (size_t)arow * K + ks * 32 + quad * 8;
            float4 a0 = *reinterpret_cast<const float4*>(hp);
            float4 a1 = *reinterpret_cast<const float4*>(hp + 4);
            a[0] = (short)f2b(a0.x); a[1] = (short)f2b(a0.y);
            a[2] = (short)f2b(a0.z); a[3] = (short)f2b(a0.w);
            a[4] = (short)f2b(a1.x); a[5] = (short)f2b(a1.y);
            a[6] = (short)f2b(a1.z); a[7] = (short)f2b(a1.w);
        } else {
            a = *reinterpret_cast<const short8*>(
                (const unsigned short*)Hv + (size_t)arow * K + ks * 32 + quad * 8);
        }
#pragma unroll
        for (int nt = 0; nt < NT; ++nt) {
            short8 b = *reinterpret_cast<const short8*>(Wp + ((nt * KS + ks) * 64 + lane) * 8);
            acc[nt] = __builtin_amdgcn_mfma_f32_16x16x32_bf16(a, b, acc[nt], 0, 0, 0);
        }
    }

#pragma unroll
    for (int reg = 0; reg < 4; ++reg) {
        int grow = waveRow + quad * 4 + reg;
        if (grow < NNODES) {
#pragma unroll
            for (int nt = 0; nt < NT; ++nt)
                Sb[(size_t)grow * N + nt * 16 + m] = f2b(acc[nt][reg]);
        }
    }
}

// ---------------------------------------------------------------------------
// INTERLEAVED fill + gemm1, 10-way groups (8 fill + 2 gemm1 tiles):
//  b = 10g + r. r<8 -> fill(chunk=g, part=b%8): within a group the 8 fill
//  blocks get all 8 parts once, and same-part blocks share b%8 -> one XCD
//  (contiguous bucket-write region, clean writebacks). r>=8 -> gemm1 tile
//  t = 2g + (r-8), exactly 782 tiles.
//  Scan: 8 edges/thread via 2x int4/float4 per stream (high MLP); matches
//  pushed as fully-formed 4B records into the LDS queue; drain = LDS read ->
//  cursor atomic -> bucket store (no scattered global loads in the chain).
// ---------------------------------------------------------------------------
__global__ __launch_bounds__(256) void fill_gemm1_kernel(
        const int* __restrict__ src, const int* __restrict__ dst,
        const float* __restrict__ val, int* __restrict__ cursor,
        unsigned int* __restrict__ buckets,
        const float* __restrict__ x, const unsigned short* __restrict__ Wp1,
        unsigned short* __restrict__ Q) {
    __shared__ unsigned int q_rec[QCAP];
    __shared__ int q_d[QCAP];
    __shared__ int qcount;

    const int g = blockIdx.x / 10;
    const int r = blockIdx.x % 10;
    if (r >= 8) {
        gemm_item<128, 128, true>(g * 2 + (r - 8), x, Wp1, Q);
        return;
    }

    if (threadIdx.x == 0) qcount = 0;
    __syncthreads();

    const int part = blockIdx.x & 7;       // XCD heuristic; all 8 parts per group
    const int lo = part * PSIZE, hi = lo + PSIZE;
    const int e0 = g * FCH + threadIdx.x * 8;

    int dd[8], ss[8];
    float vv[8];
    if (e0 + 7 < NEDGES) {
        int4 d4a = *reinterpret_cast<const int4*>(dst + e0);
        int4 d4b = *reinterpret_cast<const int4*>(dst + e0 + 4);
        int4 s4a = *reinterpret_cast<const int4*>(src + e0);
        int4 s4b = *reinterpret_cast<const int4*>(src + e0 + 4);
        float4 v4a = *reinterpret_cast<const float4*>(val + e0);
        float4 v4b = *reinterpret_cast<const float4*>(val + e0 + 4);
        dd[0] = d4a.x; dd[1] = d4a.y; dd[2] = d4a.z; dd[3] = d4a.w;
        dd[4] = d4b.x; dd[5] = d4b.y; dd[6] = d4b.z; dd[7] = d4b.w;
        ss[0] = s4a.x; ss[1] = s4a.y; ss[2] = s4a.z; ss[3] = s4a.w;
        ss[4] = s4b.x; ss[5] = s4b.y; ss[6] = s4b.z; ss[7] = s4b.w;
        vv[0] = v4a.x; vv[1] = v4a.y; vv[2] = v4a.z; vv[3] = v4a.w;
        vv[4] = v4b.x; vv[5] = v4b.y; vv[6] = v4b.z; vv[7] = v4b.w;
    } else {
#pragma unroll
        for (int i = 0; i < 8; ++i) {
            int e = e0 + i;
            if (e < NEDGES) { dd[i] = dst[e]; ss[i] = src[e]; vv[i] = val[e]; }
            else { dd[i] = -1; ss[i] = 0; vv[i] = 0.f; }
        }
    }
#pragma unroll
    for (int i = 0; i < 8; ++i) {
        int d = dd[i];
        if (d >= lo && d < hi) {
            unsigned int rec = (unsigned int)ss[i] | ((unsigned int)f2b(vv[i]) << 16);
            int pos = atomicAdd(&qcount, 1);
            if (pos < QCAP) {
                q_rec[pos] = rec;
                q_d[pos] = d;
            } else {  // overflow fallback (statistically unreachable; correct anyway)
                int p = atomicAdd(&cursor[d], 1);
                if (p < CAP) buckets[(size_t)d * CAP + p] = rec;
            }
        }
    }
    __syncthreads();

    int n = qcount < QCAP ? qcount : QCAP;
    for (int i = threadIdx.x; i < n; i += 256) {
        int d = q_d[i];
        unsigned int rec = q_rec[i];
        int p = atomicAdd(&cursor[d], 1);
        if (p < CAP) buckets[(size_t)d * CAP + p] = rec;
    }
}

// ---------------------------------------------------------------------------
// FUSED agg_i + gemm_{i+1} (occupancy-preserving): R = 2048/NIN nodes/block,
// NIN/8 threads per node; 8x edge unroll (8 independent row gathers in
// flight, plain code -> compiler-scheduled); relu'd bf16 h-tile in LDS;
// 4 waves MFMA it.
// ---------------------------------------------------------------------------
template <int NIN, int NOUT>
__global__ __launch_bounds__(256) void agg_gemm_kernel(
        const unsigned short* __restrict__ Sprev, const unsigned int* __restrict__ buckets,
        const int* __restrict__ counts, const float* __restrict__ bias,
        const unsigned short* __restrict__ Wp, unsigned short* __restrict__ Snext) {
    constexpr int NCH = NIN / 8;        // threads per node (16 or 8)
    constexpr int R = 256 / NCH;        // nodes per block (16 or 32)
    constexpr int LROW = NIN + 8;       // LDS row stride (16B-aligned pad)
    constexpr int KS = NIN / 32;
    constexpr int NT = NOUT / 16;
    constexpr int RT = R / 16;
    constexpr int TILES = RT * NT;
    __shared__ unsigned short htile[R * LROW];

    const int nodeBase = blockIdx.x * R;

    // ---- Phase A: pull-agg + bias + relu -> LDS ----
    {
        int nl = threadIdx.x / NCH;
        int cg = threadIdx.x % NCH;
        int node = nodeBase + nl;
        float acc[8];
        if (node < NNODES) {
#pragma unroll
            for (int t = 0; t < 8; ++t) acc[t] = bias[cg * 8 + t];
            int cnt = counts[node];
            if (cnt > CAP) cnt = CAP;
            const unsigned int* eb = buckets + (size_t)node * CAP;
            int j = 0;
            for (; j + 8 <= cnt; j += 8) {
                uint4 ea = *reinterpret_cast<const uint4*>(eb + j);
                uint4 ec = *reinterpret_cast<const uint4*>(eb + j + 4);
                const ushort8 m0 = *reinterpret_cast<const ushort8*>(Sprev + (size_t)(ea.x & 0xFFFF) * NIN + cg * 8);
                const ushort8 m1 = *reinterpret_cast<const ushort8*>(Sprev + (size_t)(ea.y & 0xFFFF) * NIN + cg * 8);
                const ushort8 m2 = *reinterpret_cast<const ushort8*>(Sprev + (size_t)(ea.z & 0xFFFF) * NIN + cg * 8);
                const ushort8 m3 = *reinterpret_cast<const ushort8*>(Sprev + (size_t)(ea.w & 0xFFFF) * NIN + cg * 8);
                const ushort8 m4 = *reinterpret_cast<const ushort8*>(Sprev + (size_t)(ec.x & 0xFFFF) * NIN + cg * 8);
                const ushort8 m5 = *reinterpret_cast<const ushort8*>(Sprev + (size_t)(ec.y & 0xFFFF) * NIN + cg * 8);
                const ushort8 m6 = *reinterpret_cast<const ushort8*>(Sprev + (size_t)(ec.z & 0xFFFF) * NIN + cg * 8);
                const ushort8 m7 = *reinterpret_cast<const ushort8*>(Sprev + (size_t)(ec.w & 0xFFFF) * NIN + cg * 8);
#pragma unroll
                for (int t = 0; t < 8; ++t) {
                    acc[t] = fmaf(b2f(m0[t]), recval(ea.x), acc[t]);
                    acc[t] = fmaf(b2f(m1[t]), recval(ea.y), acc[t]);
                    acc[t] = fmaf(b2f(m2[t]), recval(ea.z), acc[t]);
                    acc[t] = fmaf(b2f(m3[t]), recval(ea.w), acc[t]);
                    acc[t] = fmaf(b2f(m4[t]), recval(ec.x), acc[t]);
                    acc[t] = fmaf(b2f(m5[t]), recval(ec.y), acc[t]);
                    acc[t] = fmaf(b2f(m6[t]), recval(ec.z), acc[t]);
                    acc[t] = fmaf(b2f(m7[t]), recval(ec.w), acc[t]);
                }
            }
            for (; j + 4 <= cnt; j += 4) {
                uint4 ea = *reinterpret_cast<const uint4*>(eb + j);
                const ushort8 m0 = *reinterpret_cast<const ushort8*>(Sprev + (size_t)(ea.x & 0xFFFF) * NIN + cg * 8);
                const ushort8 m1 = *reinterpret_cast<const ushort8*>(Sprev + (size_t)(ea.y & 0xFFFF) * NIN + cg * 8);
                const ushort8 m2 = *reinterpret_cast<const ushort8*>(Sprev + (size_t)(ea.z & 0xFFFF) * NIN + cg * 8);
                const ushort8 m3 = *reinterpret_cast<const ushort8*>(Sprev + (size_t)(ea.w & 0xFFFF) * NIN + cg * 8);
#pragma unroll
                for (int t = 0; t < 8; ++t) {
                    acc[t] = fmaf(b2f(m0[t]), recval(ea.x), acc[t]);
                    acc[t] = fmaf(b2f(m1[t]), recval(ea.y), acc[t]);
                    acc[t] = fmaf(b2f(m2[t]), recval(ea.z), acc[t]);
                    acc[t] = fmaf(b2f(m3[t]), recval(ea.w), acc[t]);
                }
            }
            for (; j < cnt; ++j) {
                unsigned int rec = eb[j];
                float v = recval(rec);
                const ushort8 mr = *reinterpret_cast<const ushort8*>(Sprev + (size_t)(rec & 0xFFFF) * NIN + cg * 8);
#pragma unroll
                for (int t = 0; t < 8; ++t) acc[t] = fmaf(b2f(mr[t]), v, acc[t]);
            }
        } else {
#pragma unroll
            for (int t = 0; t < 8; ++t) acc[t] = 0.f;
        }
        ushort8 o;
#pragma unroll
        for (int t = 0; t < 8; ++t) o[t] = f2b(fmaxf(acc[t], 0.f));
        *reinterpret_cast<ushort8*>(&htile[nl * LROW + cg * 8]) = o;
    }
    __syncthreads();

    // ---- Phase B: R x NOUT MFMA GEMM on the LDS tile ----
    {
        const int lane = threadIdx.x & 63, wave = threadIdx.x >> 6;
        const int m = lane & 15, quad = lane >> 4;
        for (int t = wave; t < TILES; t += 4) {
            int rt = t / NT, nt = t % NT;
            f32x4 acc = (f32x4){0.f, 0.f, 0.f, 0.f};
#pragma unroll
            for (int ks = 0; ks < KS; ++ks) {
                short8 a = *reinterpret_cast<const short8*>(
                    &htile[(rt * 16 + m) * LROW + ks * 32 + quad * 8]);
                short8 b = *reinterpret_cast<const short8*>(Wp + ((nt * KS + ks) * 64 + lane) * 8);
                acc = __builtin_amdgcn_mfma_f32_16x16x32_bf16(a, b, acc, 0, 0, 0);
            }
#pragma unroll
            for (int reg = 0; reg < 4; ++reg) {
                int grow = nodeBase + rt * 16 + quad * 4 + reg;
                if (grow < NNODES)
                    Snext[(size_t)grow * NOUT + nt * 16 + m] = f2b(acc[reg]);
            }
        }
    }
}

// ---------------------------------------------------------------------------
// Final pull aggregation (layer 4): 32-wide, fp32 output, 8x edge unroll.
// ---------------------------------------------------------------------------
__global__ __launch_bounds__(256) void agg_out_kernel(const unsigned short* __restrict__ Sb,
        const unsigned int* __restrict__ buckets, const int* __restrict__ counts,
        const float* __restrict__ bias, float* __restrict__ outp) {
    constexpr int N = 32;
    int node = blockIdx.x * 64 + threadIdx.x / 4;
    int cg = threadIdx.x % 4;
    if (node >= NNODES) return;
    int cnt = counts[node];
    if (cnt > CAP) cnt = CAP;
    const unsigned int* eb = buckets + (size_t)node * CAP;
    float acc[8];
#pragma unroll
    for (int t = 0; t < 8; ++t) acc[t] = bias[cg * 8 + t];

    int j = 0;
    for (; j + 8 <= cnt; j += 8) {
        uint4 ea = *reinterpret_cast<const uint4*>(eb + j);
        uint4 ec = *reinterpret_cast<const uint4*>(eb + j + 4);
        const ushort8 m0 = *reinterpret_cast<const ushort8*>(Sb + (size_t)(ea.x & 0xFFFF) * N + cg * 8);
        const ushort8 m1 = *reinterpret_cast<const ushort8*>(Sb + (size_t)(ea.y & 0xFFFF) * N + cg * 8);
        const ushort8 m2 = *reinterpret_cast<const ushort8*>(Sb + (size_t)(ea.z & 0xFFFF) * N + cg * 8);
        const ushort8 m3 = *reinterpret_cast<const ushort8*>(Sb + (size_t)(ea.w & 0xFFFF) * N + cg * 8);
        const ushort8 m4 = *reinterpret_cast<const ushort8*>(Sb + (size_t)(ec.x & 0xFFFF) * N + cg * 8);
        const ushort8 m5 = *reinterpret_cast<const ushort8*>(Sb + (size_t)(ec.y & 0xFFFF) * N + cg * 8);
        const ushort8 m6 = *reinterpret_cast<const ushort8*>(Sb + (size_t)(ec.z & 0xFFFF) * N + cg * 8);
        const ushort8 m7 = *reinterpret_cast<const ushort8*>(Sb + (size_t)(ec.w & 0xFFFF) * N + cg * 8);
#pragma unroll
        for (int t = 0; t < 8; ++t) {
            acc[t] = fmaf(b2f(m0[t]), recval(ea.x), acc[t]);
            acc[t] = fmaf(b2f(m1[t]), recval(ea.y), acc[t]);
            acc[t] = fmaf(b2f(m2[t]), recval(ea.z), acc[t]);
            acc[t] = fmaf(b2f(m3[t]), recval(ea.w), acc[t]);
            acc[t] = fmaf(b2f(m4[t]), recval(ec.x), acc[t]);
            acc[t] = fmaf(b2f(m5[t]), recval(ec.y), acc[t]);
            acc[t] = fmaf(b2f(m6[t]), recval(ec.z), acc[t]);
            acc[t] = fmaf(b2f(m7[t]), recval(ec.w), acc[t]);
        }
    }
    for (; j + 4 <= cnt; j += 4) {
        uint4 ea = *reinterpret_cast<const uint4*>(eb + j);
        const ushort8 m0 = *reinterpret_cast<const ushort8*>(Sb + (size_t)(ea.x & 0xFFFF) * N + cg * 8);
        const ushort8 m1 = *reinterpret_cast<const ushort8*>(Sb + (size_t)(ea.y & 0xFFFF) * N + cg * 8);
        const ushort8 m2 = *reinterpret_cast<const ushort8*>(Sb + (size_t)(ea.z & 0xFFFF) * N + cg * 8);
        const ushort8 m3 = *reinterpret_cast<const ushort8*>(Sb + (size_t)(ea.w & 0xFFFF) * N + cg * 8);
#pragma unroll
        for (int t = 0; t < 8; ++t) {
            acc[t] = fmaf(b2f(m0[t]), recval(ea.x), acc[t]);
            acc[t] = fmaf(b2f(m1[t]), recval(ea.y), acc[t]);
            acc[t] = fmaf(b2f(m2[t]), recval(ea.z), acc[t]);
            acc[t] = fmaf(b2f(m3[t]), recval(ea.w), acc[t]);
        }
    }
    for (; j < cnt; ++j) {
        unsigned int rec = eb[j];
        float v = recval(rec);
        const ushort8 mr = *reinterpret_cast<const ushort8*>(Sb + (size_t)(rec & 0xFFFF) * N + cg * 8);
#pragma unroll
        for (int t = 0; t < 8; ++t) acc[t] = fmaf(b2f(mr[t]), v, acc[t]);
    }

    float* op = outp + (size_t)node * N + cg * 8;
    *reinterpret_cast<float4*>(op) = make_float4(acc[0], acc[1], acc[2], acc[3]);
    *reinterpret_cast<float4*>(op + 4) = make_float4(acc[4], acc[5], acc[6], acc[7]);
}

extern "C" void kernel_launch(void* const* d_in, const int* in_sizes, int n_in,
                              void* d_out, int out_size, void* d_ws, size_t ws_size,
                              hipStream_t stream) {
    const float* x   = (const float*)d_in[0];
    const int*   src = (const int*)d_in[1];
    const int*   dst = (const int*)d_in[2];
    const float* val = (const float*)d_in[3];
    const float* W1  = (const float*)d_in[4];
    const float* b1  = (const float*)d_in[5];
    const float* W2  = (const float*)d_in[6];
    const float* b2  = (const float*)d_in[7];
    const float* W3  = (const float*)d_in[8];
    const float* b3  = (const float*)d_in[9];
    const float* W4  = (const float*)d_in[10];
    const float* b4  = (const float*)d_in[11];
    float* out = (float*)d_out;

    unsigned short* P = (unsigned short*)d_ws;            // bf16 50000x128
    unsigned short* Q = P + (size_t)NNODES * 128;         // bf16 50000x128
    unsigned int* buckets = (unsigned int*)(Q + (size_t)NNODES * 128);  // u32 x 50000*64 = 12.8 MB
    unsigned short* Wp1 = (unsigned short*)(buckets + (size_t)NNODES * CAP);
    unsigned short* Wp2 = Wp1 + 128 * 128;
    unsigned short* Wp3 = Wp2 + 128 * 128;
    unsigned short* Wp4 = Wp3 + 128 * 64;
    int* cursor = (int*)(Wp4 + 64 * 32);                  // NNODES (counter, then degree)

    const dim3 blk(256);

    hipMemsetAsync(cursor, 0, NNODES * sizeof(int), stream);
    prep_kernel<<<(PACK_TOT + 255) / 256, blk, 0, stream>>>(W1, W2, W3, W4,
                                                            Wp1, Wp2, Wp3, Wp4);
    // interleaved fill + gemm1 (10-way): 391*10 blocks
    fill_gemm1_kernel<<<CHUNKS * 10, blk, 0, stream>>>(
        src, dst, val, cursor, buckets, x, Wp1, Q);
    // agg1 + gemm2 : S2 = (relu(agg(Q)+b1)) @ W2 -> P
    agg_gemm_kernel<128, 128><<<(NNODES + 15) / 16, blk, 0, stream>>>(
        Q, buckets, cursor, b1, Wp2, P);
    // agg2 + gemm3 : S3 = (relu(agg(P)+b2)) @ W3 -> Q
    agg_gemm_kernel<128, 64><<<(NNODES + 15) / 16, blk, 0, stream>>>(
        P, buckets, cursor, b2, Wp3, Q);
    // agg3 + gemm4 : S4 = (relu(agg(Q)+b3)) @ W4 -> P
    agg_gemm_kernel<64, 32><<<(NNODES + 31) / 32, blk, 0, stream>>>(
        Q, buckets, cursor, b3, Wp4, P);
    // agg4 : out = agg(P) + b4 (fp32)
    agg_out_kernel<<<(NNODES + 63) / 64, blk, 0, stream>>>(P, buckets, cursor, b4, out);
}